// Round 1
// baseline (5636.177 us; speedup 1.0000x reference)
//
#include <hip/hip_runtime.h>
#include <math.h>

#define B_    2
#define S_    2048
#define HID_  1024
#define H_    16
#define D_    64
#define KEEP_ 204
#define QT_   8

// order-preserving fp32 -> uint32 mapping (larger float <=> larger uint)
__device__ __forceinline__ unsigned f2u_ord(float x) {
    unsigned b = __float_as_uint(x);
    return (b & 0x80000000u) ? ~b : (b | 0x80000000u);
}

// ---------------- GEMM: Y = A @ W + bias ----------------
// A [M, Kd] row-major, W [Kd, N] row-major.
// MODE 0: Y[m*N + n]
// MODE 1: scatter heads: m=(b,s), n=(h,d) -> Y[((b*H_+h)*S_+s)*D_+d]
template <int MODE>
__global__ __launch_bounds__(256) void gemm_f32_k(
    const float* __restrict__ A, const float* __restrict__ W,
    const float* __restrict__ bias, float* __restrict__ Y,
    int M, int N, int Kd)
{
    __shared__ __align__(16) float As[16][64];
    __shared__ __align__(16) float Bs[16][64];
    const int tid = threadIdx.x;
    const int tx = tid & 15, ty = tid >> 4;
    const int n0 = blockIdx.x * 64, m0 = blockIdx.y * 64;
    float acc[4][4] = {};
    for (int k0 = 0; k0 < Kd; k0 += 16) {
        {
            const int c4 = tid & 3, r = tid >> 2;
            const float4 a4 = *(const float4*)&A[(m0 + r) * Kd + k0 + c4 * 4];
            As[c4*4+0][r] = a4.x; As[c4*4+1][r] = a4.y;
            As[c4*4+2][r] = a4.z; As[c4*4+3][r] = a4.w;
        }
        {
            const int r4 = tid & 15, c = tid >> 4;
            *(float4*)&Bs[c][r4*4] = *(const float4*)&W[(k0 + c) * N + n0 + r4*4];
        }
        __syncthreads();
        #pragma unroll
        for (int kk = 0; kk < 16; kk++) {
            const float4 a4 = *(const float4*)&As[kk][ty*4];
            const float4 b4 = *(const float4*)&Bs[kk][tx*4];
            const float av[4] = {a4.x, a4.y, a4.z, a4.w};
            const float bv[4] = {b4.x, b4.y, b4.z, b4.w};
            #pragma unroll
            for (int i = 0; i < 4; i++)
                #pragma unroll
                for (int j = 0; j < 4; j++)
                    acc[i][j] = fmaf(av[i], bv[j], acc[i][j]);
        }
        __syncthreads();
    }
    if (MODE == 0) {
        #pragma unroll
        for (int i = 0; i < 4; i++) {
            const int m = m0 + ty*4 + i;
            float4 o;
            o.x = acc[i][0] + bias[n0+tx*4+0];
            o.y = acc[i][1] + bias[n0+tx*4+1];
            o.z = acc[i][2] + bias[n0+tx*4+2];
            o.w = acc[i][3] + bias[n0+tx*4+3];
            *(float4*)&Y[m * N + n0 + tx*4] = o;
        }
    } else {
        #pragma unroll
        for (int i = 0; i < 4; i++) {
            const int m = m0 + ty*4 + i;
            const int b = m >> 11, s = m & (S_ - 1);
            #pragma unroll
            for (int j = 0; j < 4; j++) {
                const int n = n0 + tx*4 + j;
                const int h = n >> 6, d = n & 63;
                Y[((b * H_ + h) * S_ + s) * D_ + d] = acc[i][j] + bias[n];
            }
        }
    }
}

// ---------------- sumV[bh][d] = sum_j V[bh][j][d] ----------------
__global__ __launch_bounds__(256) void sumv_k(const float* __restrict__ V,
                                              float* __restrict__ sumV)
{
    const int bh = blockIdx.x;
    const int d = threadIdx.x & 63;
    const int g = threadIdx.x >> 6;      // 4 row-groups
    float acc = 0.f;
    for (int j = g; j < S_; j += 4)
        acc += V[(bh * S_ + j) * D_ + d];
    __shared__ float part[4][D_];
    part[g][d] = acc;
    __syncthreads();
    if (threadIdx.x < 64)
        sumV[bh * D_ + d] = part[0][d] + part[1][d] + part[2][d] + part[3][d];
}

// ---------------- fused scores + exact top-204 + sparse-softmax AV ----------------
// block: 256 threads, handles QT_=8 query rows of one (b,h).
__global__ __launch_bounds__(256) void attn_topk_k(
    const float* __restrict__ Q, const float* __restrict__ Kg,
    const float* __restrict__ V, const float* __restrict__ sumV,
    float* __restrict__ AO)
{
    const int tid = threadIdx.x;
    const int bh = blockIdx.x >> 8;            // S_/QT_ = 256 q-tiles per (b,h)
    const int q0 = (blockIdx.x & 255) * QT_;
    const int b = bh >> 4, h = bh & (H_ - 1);

    __shared__ __align__(16) float sc[QT_][S_];   // 64 KB scores
    __shared__ __align__(16) float qs[QT_][D_];
    __shared__ unsigned hist[256];
    __shared__ float red[256];
    __shared__ int   list_j[224];
    __shared__ float list_w[224];
    __shared__ float part[2][4][D_];
    __shared__ unsigned ctrs[4];

    for (int i = tid; i < QT_ * D_; i += 256)
        qs[i >> 6][i & 63] = Q[(bh * S_ + q0 + (i >> 6)) * D_ + (i & 63)];
    __syncthreads();

    // ---- scores: thread covers 4 q rows (wave-uniform half) x 16 j's ----
    {
        const int qh = tid >> 7;        // 0..1, uniform per wave
        const int jl = tid & 127;
        float acc[4][16];
        #pragma unroll
        for (int qq = 0; qq < 4; qq++)
            #pragma unroll
            for (int i = 0; i < 16; i++) acc[qq][i] = 0.f;
        #pragma unroll
        for (int db = 0; db < 4; db++) {        // 16-dim chunks of D
            float4 qv[4][4];
            #pragma unroll
            for (int qq = 0; qq < 4; qq++)
                #pragma unroll
                for (int dd = 0; dd < 4; dd++)
                    qv[qq][dd] = *(const float4*)&qs[qh*4+qq][db*16 + dd*4];
            for (int i = 0; i < 16; i++) {
                const float4* kp = (const float4*)&Kg[(bh * S_ + jl + 128*i) * D_];
                float4 kv[4];
                #pragma unroll
                for (int dd = 0; dd < 4; dd++) kv[dd] = kp[db*4 + dd];   // 64B/lane
                #pragma unroll
                for (int qq = 0; qq < 4; qq++) {
                    float s = 0.f;
                    #pragma unroll
                    for (int dd = 0; dd < 4; dd++) {
                        s = fmaf(kv[dd].x, qv[qq][dd].x, s);
                        s = fmaf(kv[dd].y, qv[qq][dd].y, s);
                        s = fmaf(kv[dd].z, qv[qq][dd].z, s);
                        s = fmaf(kv[dd].w, qv[qq][dd].w, s);
                    }
                    acc[qq][i] += s;
                }
            }
        }
        #pragma unroll
        for (int qq = 0; qq < 4; qq++)
            for (int i = 0; i < 16; i++)
                sc[qh*4+qq][jl + 128*i] = acc[qq][i] * 0.125f;   // 1/sqrt(64)
    }
    __syncthreads();

    // ---- per-row: exact top-KEEP_ via radix select, then sparse softmax AV ----
    for (int qr = 0; qr < QT_; qr++) {
        float val[8];
        unsigned uu[8];
        #pragma unroll
        for (int i = 0; i < 8; i++) {
            val[i] = sc[qr][tid + 256*i];
            uu[i] = f2u_ord(val[i]);
        }
        // row max
        float lm = val[0];
        #pragma unroll
        for (int i = 1; i < 8; i++) lm = fmaxf(lm, val[i]);
        red[tid] = lm;
        __syncthreads();
        for (int s = 128; s > 0; s >>= 1) {
            if (tid < s) red[tid] = fmaxf(red[tid], red[tid + s]);
            __syncthreads();
        }
        const float m = fmaxf(red[0], 0.0f);   // sparse row includes zeros
        __syncthreads();

        // radix select: exact bit pattern T of the 204th largest; rem = #ties to take
        unsigned prefix = 0;
        int rem = KEEP_;
        for (int pass = 3; pass >= 0; pass--) {
            const int shift = pass * 8;
            hist[tid] = 0;
            __syncthreads();
            #pragma unroll
            for (int i = 0; i < 8; i++) {
                const unsigned u = uu[i];
                const bool match = (pass == 3) || ((u >> (shift + 8)) == (prefix >> (shift + 8)));
                if (match) atomicAdd(&hist[(u >> shift) & 255], 1u);
            }
            __syncthreads();
            // inclusive suffix scan of hist (count >= bin)
            unsigned sfx = hist[tid];
            for (int off = 1; off < 256; off <<= 1) {
                const unsigned v = (tid + off < 256) ? hist[tid + off] : 0u;
                __syncthreads();
                sfx += v;
                hist[tid] = sfx;
                __syncthreads();
            }
            const unsigned cge = hist[tid];
            const unsigned cgt = (tid < 255) ? hist[tid + 1] : 0u;
            if (cge >= (unsigned)rem && cgt < (unsigned)rem) {  // unique boundary bin
                ctrs[0] = (unsigned)tid;
                ctrs[1] = cgt;
            }
            __syncthreads();
            prefix |= ctrs[0] << shift;
            rem -= (int)ctrs[1];
            __syncthreads();
        }
        const unsigned T = prefix;

        // build selected list: all > T, plus `rem` of == T (lowest index, jax tie-break)
        if (tid == 0) { ctrs[0] = 0; ctrs[1] = 0; }
        __syncthreads();
        #pragma unroll
        for (int i = 0; i < 8; i++) {
            if (uu[i] > T) {
                const int p = (int)atomicAdd(&ctrs[0], 1u);
                list_j[p] = tid + 256*i;
            } else if (uu[i] == T) {
                atomicAdd(&ctrs[1], 1u);
            }
        }
        __syncthreads();
        const int neq = (int)ctrs[1];
        if (neq == rem) {      // normal case: take all ties
            #pragma unroll
            for (int i = 0; i < 8; i++) {
                if (uu[i] == T) {
                    const int p = (int)atomicAdd(&ctrs[0], 1u);
                    list_j[p] = tid + 256*i;
                }
            }
        } else if (tid == 0) { // rare exact-tie overflow: ordered scan
            int need = rem;
            int p = (int)ctrs[0];
            for (int j = 0; j < S_ && need > 0; j++) {
                if (f2u_ord(sc[qr][j]) == T) { list_j[p++] = j; need--; }
            }
            ctrs[0] = (unsigned)p;
        }
        __syncthreads();
        const int L = (int)ctrs[0];   // == KEEP_

        // weights + E = sum of selected exp(v-m)
        float esum = 0.f;
        for (int p = tid; p < L; p += 256) {
            const float w = __expf(sc[qr][list_j[p]] - m);
            list_w[p] = w;
            esum += w;
        }
        red[tid] = esum;
        __syncthreads();
        for (int s = 128; s > 0; s >>= 1) {
            if (tid < s) red[tid] += red[tid + s];
            __syncthreads();
        }
        const float E = red[0];

        // AV gather: 4 groups x 64 d-lanes
        const int g = tid >> 6, d = tid & 63;
        float accW = 0.f, accS = 0.f;
        for (int p = g; p < L; p += 4) {
            const float vv = V[(bh * S_ + list_j[p]) * D_ + d];
            accW = fmaf(list_w[p], vv, accW);
            accS += vv;
        }
        part[0][g][d] = accW;
        part[1][g][d] = accS;
        __syncthreads();
        if (tid < 64) {
            const float Wd = part[0][0][tid] + part[0][1][tid] + part[0][2][tid] + part[0][3][tid];
            const float Sd = part[1][0][tid] + part[1][1][tid] + part[1][2][tid] + part[1][3][tid];
            const float em = __expf(-m);                       // weight of a zero entry
            const float denom = E + (float)(S_ - KEEP_) * em;
            const float numer = Wd + em * (sumV[bh * D_ + tid] - Sd);
            AO[(b * S_ + q0 + qr) * HID_ + h * D_ + tid] = numer / denom;
        }
        __syncthreads();
    }
}

extern "C" void kernel_launch(void* const* d_in, const int* in_sizes, int n_in,
                              void* d_out, int out_size, void* d_ws, size_t ws_size,
                              hipStream_t stream) {
    const float* x  = (const float*)d_in[0];
    const float* Wq = (const float*)d_in[1];
    const float* bq = (const float*)d_in[2];
    const float* Wk = (const float*)d_in[3];
    const float* bk = (const float*)d_in[4];
    const float* Wv = (const float*)d_in[5];
    const float* bv = (const float*)d_in[6];
    const float* Wo = (const float*)d_in[7];
    const float* bo = (const float*)d_in[8];
    float* out = (float*)d_out;

    float* ws = (float*)d_ws;
    const size_t NQ = (size_t)B_ * H_ * S_ * D_;   // 4,194,304 floats
    float* Qw = ws;
    float* Kw = ws + NQ;
    float* Vw = ws + 2 * NQ;
    float* AO = ws + 3 * NQ;
    float* sV = ws + 4 * NQ;                       // B_*H_*D_ = 2048 floats

    dim3 blk(256);
    dim3 gg(HID_ / 64, (B_ * S_) / 64);
    gemm_f32_k<1><<<gg, blk, 0, stream>>>(x, Wq, bq, Qw, B_ * S_, HID_, HID_);
    gemm_f32_k<1><<<gg, blk, 0, stream>>>(x, Wk, bk, Kw, B_ * S_, HID_, HID_);
    gemm_f32_k<1><<<gg, blk, 0, stream>>>(x, Wv, bv, Vw, B_ * S_, HID_, HID_);
    sumv_k<<<dim3(B_ * H_), blk, 0, stream>>>(Vw, sV);
    attn_topk_k<<<dim3(B_ * H_ * (S_ / QT_)), blk, 0, stream>>>(Qw, Kw, Vw, sV, AO);
    gemm_f32_k<0><<<gg, blk, 0, stream>>>(AO, Wo, bo, out, B_ * S_, HID_, HID_);
}

// Round 2
// 3197.117 us; speedup vs baseline: 1.7629x; 1.7629x over previous
//
#include <hip/hip_runtime.h>
#include <math.h>

#define B_    2
#define S_    2048
#define HID_  1024
#define H_    16
#define D_    64
#define KEEP_ 204
#define QT_   8

// order-preserving fp32 -> uint32 mapping (larger float <=> larger uint)
__device__ __forceinline__ unsigned f2u_ord(float x) {
    unsigned b = __float_as_uint(x);
    return (b & 0x80000000u) ? ~b : (b | 0x80000000u);
}
__device__ __forceinline__ float u2f_ord(unsigned u) {
    unsigned b = (u & 0x80000000u) ? (u ^ 0x80000000u) : ~u;
    return __uint_as_float(b);
}
__device__ __forceinline__ float wave_sum(float x) {
    #pragma unroll
    for (int off = 32; off > 0; off >>= 1) x += __shfl_xor(x, off);
    return x;
}
__device__ __forceinline__ float wave_max(float x) {
    #pragma unroll
    for (int off = 32; off > 0; off >>= 1) x = fmaxf(x, __shfl_xor(x, off));
    return x;
}

// ---------------- GEMM: Y = A @ W + bias ----------------
template <int MODE>
__global__ __launch_bounds__(256) void gemm_f32_k(
    const float* __restrict__ A, const float* __restrict__ W,
    const float* __restrict__ bias, float* __restrict__ Y,
    int M, int N, int Kd)
{
    __shared__ __align__(16) float As[16][64];
    __shared__ __align__(16) float Bs[16][64];
    const int tid = threadIdx.x;
    const int tx = tid & 15, ty = tid >> 4;
    const int n0 = blockIdx.x * 64, m0 = blockIdx.y * 64;
    float acc[4][4] = {};
    for (int k0 = 0; k0 < Kd; k0 += 16) {
        {
            const int c4 = tid & 3, r = tid >> 2;
            const float4 a4 = *(const float4*)&A[(m0 + r) * Kd + k0 + c4 * 4];
            As[c4*4+0][r] = a4.x; As[c4*4+1][r] = a4.y;
            As[c4*4+2][r] = a4.z; As[c4*4+3][r] = a4.w;
        }
        {
            const int r4 = tid & 15, c = tid >> 4;
            *(float4*)&Bs[c][r4*4] = *(const float4*)&W[(k0 + c) * N + n0 + r4*4];
        }
        __syncthreads();
        #pragma unroll
        for (int kk = 0; kk < 16; kk++) {
            const float4 a4 = *(const float4*)&As[kk][ty*4];
            const float4 b4 = *(const float4*)&Bs[kk][tx*4];
            const float av[4] = {a4.x, a4.y, a4.z, a4.w};
            const float bv[4] = {b4.x, b4.y, b4.z, b4.w};
            #pragma unroll
            for (int i = 0; i < 4; i++)
                #pragma unroll
                for (int j = 0; j < 4; j++)
                    acc[i][j] = fmaf(av[i], bv[j], acc[i][j]);
        }
        __syncthreads();
    }
    if (MODE == 0) {
        #pragma unroll
        for (int i = 0; i < 4; i++) {
            const int m = m0 + ty*4 + i;
            float4 o;
            o.x = acc[i][0] + bias[n0+tx*4+0];
            o.y = acc[i][1] + bias[n0+tx*4+1];
            o.z = acc[i][2] + bias[n0+tx*4+2];
            o.w = acc[i][3] + bias[n0+tx*4+3];
            *(float4*)&Y[m * N + n0 + tx*4] = o;
        }
    } else {
        #pragma unroll
        for (int i = 0; i < 4; i++) {
            const int m = m0 + ty*4 + i;
            const int b = m >> 11, s = m & (S_ - 1);
            #pragma unroll
            for (int j = 0; j < 4; j++) {
                const int n = n0 + tx*4 + j;
                const int h = n >> 6, d = n & 63;
                Y[((b * H_ + h) * S_ + s) * D_ + d] = acc[i][j] + bias[n];
            }
        }
    }
}

// ---------------- sumV[bh][d] = sum_j V[bh][j][d] ----------------
__global__ __launch_bounds__(256) void sumv_k(const float* __restrict__ V,
                                              float* __restrict__ sumV)
{
    const int bh = blockIdx.x;
    const int d = threadIdx.x & 63;
    const int g = threadIdx.x >> 6;
    float acc = 0.f;
    for (int j = g; j < S_; j += 4)
        acc += V[(bh * S_ + j) * D_ + d];
    __shared__ float part[4][D_];
    part[g][d] = acc;
    __syncthreads();
    if (threadIdx.x < 64)
        sumV[bh * D_ + d] = part[0][d] + part[1][d] + part[2][d] + part[3][d];
}

// ---------------- fused scores + exact top-204 + sparse-softmax AV ----------------
// 256 threads = 4 waves per block; cooperative scores, then each wave owns
// 2 query rows with ZERO block barriers (wave-private hist/list, shuffle
// reductions, ballot compaction).
__global__ __launch_bounds__(256, 2) void attn_topk_k(
    const float* __restrict__ Q, const float* __restrict__ Kg,
    const float* __restrict__ V, const float* __restrict__ sumV,
    float* __restrict__ AO)
{
    const int tid = threadIdx.x;
    const int wv = tid >> 6;
    const int lane = tid & 63;
    const int bh = blockIdx.x >> 8;            // S_/QT_ = 256 q-tiles per (b,h)
    const int q0 = (blockIdx.x & 255) * QT_;
    const int b = bh >> 4, h = bh & (H_ - 1);

    __shared__ __align__(16) float sc[QT_][S_];      // 64 KB
    __shared__ __align__(16) float qs[QT_][D_];
    __shared__ __align__(16) unsigned hist[4][256];  // wave-private
    __shared__ __align__(16) int   list_j[4][224];   // wave-private
    __shared__ __align__(16) float list_w[4][224];

    for (int i = tid; i < QT_ * D_; i += 256)
        qs[i >> 6][i & 63] = Q[(bh * S_ + q0 + (i >> 6)) * D_ + (i & 63)];
    __syncthreads();

    // ---- cooperative scores: thread covers 4 q rows x 16 j's ----
    {
        const int qh = tid >> 7;
        const int jl = tid & 127;
        float acc[4][16];
        #pragma unroll
        for (int qq = 0; qq < 4; qq++)
            #pragma unroll
            for (int i = 0; i < 16; i++) acc[qq][i] = 0.f;
        #pragma unroll
        for (int db = 0; db < 4; db++) {
            float4 qv[4][4];
            #pragma unroll
            for (int qq = 0; qq < 4; qq++)
                #pragma unroll
                for (int dd = 0; dd < 4; dd++)
                    qv[qq][dd] = *(const float4*)&qs[qh*4+qq][db*16 + dd*4];
            for (int i = 0; i < 16; i++) {
                const float4* kp = (const float4*)&Kg[(bh * S_ + jl + 128*i) * D_];
                float4 kv[4];
                #pragma unroll
                for (int dd = 0; dd < 4; dd++) kv[dd] = kp[db*4 + dd];
                #pragma unroll
                for (int qq = 0; qq < 4; qq++) {
                    float s = 0.f;
                    #pragma unroll
                    for (int dd = 0; dd < 4; dd++) {
                        s = fmaf(kv[dd].x, qv[qq][dd].x, s);
                        s = fmaf(kv[dd].y, qv[qq][dd].y, s);
                        s = fmaf(kv[dd].z, qv[qq][dd].z, s);
                        s = fmaf(kv[dd].w, qv[qq][dd].w, s);
                    }
                    acc[qq][i] += s;
                }
            }
        }
        #pragma unroll
        for (int qq = 0; qq < 4; qq++)
            for (int i = 0; i < 16; i++)
                sc[qh*4+qq][jl + 128*i] = acc[qq][i] * 0.125f;
    }
    __syncthreads();

    const float* Vb = V + (size_t)bh * S_ * D_;

    for (int rr = 0; rr < 2; rr++) {
        const int qr = wv * 2 + rr;

        // row into registers: lane owns j = i*256 + lane*4 + k
        float4 v4[8];
        #pragma unroll
        for (int i = 0; i < 8; i++)
            v4[i] = *(const float4*)&sc[qr][i * 256 + lane * 4];

        float lm = -INFINITY;
        #pragma unroll
        for (int i = 0; i < 8; i++)
            lm = fmaxf(lm, fmaxf(fmaxf(v4[i].x, v4[i].y), fmaxf(v4[i].z, v4[i].w)));
        const float m = fmaxf(wave_max(lm), 0.0f);   // sparse row includes zeros

        // ---- exact radix select (wave-private, barrier-free) ----
        unsigned prefix = 0;
        int rem = KEEP_;
        #pragma unroll
        for (int pass = 3; pass >= 0; pass--) {
            const int shift = pass * 8;
            *(uint4*)&hist[wv][lane * 4] = make_uint4(0u, 0u, 0u, 0u);
            #pragma unroll
            for (int i = 0; i < 8; i++) {
                const float vv[4] = {v4[i].x, v4[i].y, v4[i].z, v4[i].w};
                #pragma unroll
                for (int k = 0; k < 4; k++) {
                    const unsigned u = f2u_ord(vv[k]);
                    const bool match = (pass == 3) ||
                        ((u >> (shift + 8)) == (prefix >> (shift + 8)));
                    if (match) atomicAdd(&hist[wv][(u >> shift) & 255u], 1u);
                }
            }
            const uint4 h4 = *(const uint4*)&hist[wv][lane * 4];
            const unsigned s3 = h4.w;
            const unsigned s2 = h4.z + s3;
            const unsigned s1 = h4.y + s2;
            const unsigned s0 = h4.x + s1;
            unsigned incl = s0;                       // suffix scan across lanes
            #pragma unroll
            for (int off = 1; off < 64; off <<= 1) {
                const unsigned t = __shfl_down(incl, off);
                if (lane + off < 64) incl += t;
            }
            const unsigned excl = incl - s0;
            const unsigned cge[4] = {excl + s0, excl + s1, excl + s2, excl + s3};
            const unsigned cgt[4] = {excl + s1, excl + s2, excl + s3, excl};
            unsigned pk = 0;
            bool found = false;
            #pragma unroll
            for (int k = 0; k < 4; k++) {
                if (cge[k] >= (unsigned)rem && cgt[k] < (unsigned)rem) {
                    found = true;
                    pk = ((unsigned)(lane * 4 + k) << 16) | cgt[k];
                }
            }
            const unsigned long long fm = __ballot(found);
            const int src = __builtin_ctzll(fm);
            pk = __shfl(pk, src);
            prefix |= (pk >> 16) << shift;
            rem -= (int)(pk & 0xffffu);
        }
        const unsigned T = prefix;
        const float expT = __expf(u2f_ord(T) - m);

        // ---- build list via ballot compaction (no atomics) ----
        float esum = 0.f;
        int base = 0;
        int eqTotal = 0;
        #pragma unroll
        for (int i = 0; i < 8; i++) {
            const float vv[4] = {v4[i].x, v4[i].y, v4[i].z, v4[i].w};
            #pragma unroll
            for (int k = 0; k < 4; k++) {
                const unsigned u = f2u_ord(vv[k]);
                const bool gt = u > T;
                const unsigned long long mg = __ballot(gt);
                if (gt) {
                    const int pos = base + (int)__popcll(mg & ((1ULL << lane) - 1ULL));
                    const float w = __expf(vv[k] - m);
                    list_j[wv][pos] = i * 256 + lane * 4 + k;
                    list_w[wv][pos] = w;
                    esum += w;
                }
                base += (int)__popcll(mg);
                eqTotal += (int)__popcll(__ballot(u == T));
            }
        }
        if (eqTotal == rem) {            // normal: take all ties
            #pragma unroll
            for (int i = 0; i < 8; i++) {
                const float vv[4] = {v4[i].x, v4[i].y, v4[i].z, v4[i].w};
                #pragma unroll
                for (int k = 0; k < 4; k++) {
                    const unsigned u = f2u_ord(vv[k]);
                    const bool eq = (u == T);
                    const unsigned long long mg = __ballot(eq);
                    if (eq) {
                        const int pos = base + (int)__popcll(mg & ((1ULL << lane) - 1ULL));
                        list_j[wv][pos] = i * 256 + lane * 4 + k;
                        list_w[wv][pos] = expT;
                    }
                    base += (int)__popcll(mg);
                }
            }
        } else if (lane == 0) {          // rare tie overflow: lowest-index order
            int p = base, need = rem;
            for (int j = 0; j < S_ && need > 0; j++) {
                if (f2u_ord(sc[qr][j]) == T) {
                    list_j[wv][p] = j; list_w[wv][p] = expT; p++; need--;
                }
            }
        }
        const float E = wave_sum(esum) + (float)rem * expT;

        __asm__ volatile("s_waitcnt lgkmcnt(0)" ::: "memory");

        // ---- AV gather: lane = d, loop over 204 selected (51 x 4) ----
        float accW = 0.f, accS = 0.f;
        #pragma unroll 1
        for (int p = 0; p < KEEP_; p += 4) {
            const int4   j4 = *(const int4*)&list_j[wv][p];
            const float4 w4 = *(const float4*)&list_w[wv][p];
            const float a0 = Vb[j4.x * 64 + lane];
            const float a1 = Vb[j4.y * 64 + lane];
            const float a2 = Vb[j4.z * 64 + lane];
            const float a3 = Vb[j4.w * 64 + lane];
            accW = fmaf(w4.x, a0, accW);
            accW = fmaf(w4.y, a1, accW);
            accW = fmaf(w4.z, a2, accW);
            accW = fmaf(w4.w, a3, accW);
            accS += a0 + a1 + a2 + a3;
        }
        const float em = __expf(-m);
        const float denom = E + (float)(S_ - KEEP_) * em;
        const float numer = accW + em * (sumV[bh * D_ + lane] - accS);
        AO[(b * S_ + q0 + qr) * HID_ + h * D_ + lane] = numer / denom;
    }
}

extern "C" void kernel_launch(void* const* d_in, const int* in_sizes, int n_in,
                              void* d_out, int out_size, void* d_ws, size_t ws_size,
                              hipStream_t stream) {
    const float* x  = (const float*)d_in[0];
    const float* Wq = (const float*)d_in[1];
    const float* bq = (const float*)d_in[2];
    const float* Wk = (const float*)d_in[3];
    const float* bk = (const float*)d_in[4];
    const float* Wv = (const float*)d_in[5];
    const float* bv = (const float*)d_in[6];
    const float* Wo = (const float*)d_in[7];
    const float* bo = (const float*)d_in[8];
    float* out = (float*)d_out;

    float* ws = (float*)d_ws;
    const size_t NQ = (size_t)B_ * H_ * S_ * D_;
    float* Qw = ws;
    float* Kw = ws + NQ;
    float* Vw = ws + 2 * NQ;
    float* AO = ws + 3 * NQ;
    float* sV = ws + 4 * NQ;

    dim3 blk(256);
    dim3 gg(HID_ / 64, (B_ * S_) / 64);
    gemm_f32_k<1><<<gg, blk, 0, stream>>>(x, Wq, bq, Qw, B_ * S_, HID_, HID_);
    gemm_f32_k<1><<<gg, blk, 0, stream>>>(x, Wk, bk, Kw, B_ * S_, HID_, HID_);
    gemm_f32_k<1><<<gg, blk, 0, stream>>>(x, Wv, bv, Vw, B_ * S_, HID_, HID_);
    sumv_k<<<dim3(B_ * H_), blk, 0, stream>>>(Vw, sV);
    attn_topk_k<<<dim3(B_ * H_ * (S_ / QT_)), blk, 0, stream>>>(Qw, Kw, Vw, sV, AO);
    gemm_f32_k<0><<<gg, blk, 0, stream>>>(AO, Wo, bo, out, B_ * S_, HID_, HID_);
}